// Round 13
// baseline (108.186 us; speedup 1.0000x reference)
//
#include <hip/hip_runtime.h>
#include <hip/hip_bf16.h>

#define ATTN_N 8192
#define ATTN_D 128
#define TKEYS 32                      // keys per LDS tile
#define NTILES (ATTN_N / TKEYS)       // 256
#define TILE_ELEMS (TKEYS * ATTN_D)   // 4096 bf16 = 8 KB
#define QROWS 256                     // queries per block (8 waves x 32 rows)
#define SPLITK 8                      // 8-way split-K -> 256 blocks = 1/CU
#define KTPB (NTILES / SPLITK)        // 32 key tiles per block
#define NBUF 8                        // 8-deep LDS ring (128 KB)
#define PERIOD 4                      // tiles per barrier super-period

typedef __bf16 bf16_t;
typedef bf16_t bf16x8 __attribute__((ext_vector_type(8)));
typedef float f32x4 __attribute__((ext_vector_type(4)));

#if __has_builtin(__builtin_amdgcn_exp2f)
#define EXP2(x) __builtin_amdgcn_exp2f(x)
#else
#define EXP2(x) __expf((x) * 0.6931471805599453f)
#endif

// Async global->LDS DMA, 16 B per lane; lane-linear on both sides (m104).
__device__ __forceinline__ void dma16(const bf16_t* g, bf16_t* l) {
  __builtin_amdgcn_global_load_lds(
      (const __attribute__((address_space(1))) void*)g,
      (__attribute__((address_space(3))) void*)l, 16, 0, 0);
}

// ---------------------------------------------------------------------------
// Prep (R6 version, verified): Q -> bf16 linear (scaled by log2(e)/sqrt(128));
//   K -> key-linear swizzled image (16B chunk j at j ^ (key&15));
//   V -> transposed 32-key tile image vtswz: tile = key/32 is
//   [d=0..127][key-slot 0..31]; chunk cq holds phys keys 4cq+{0..3} and
//   16+4cq+{0..3} (quad-block interleave matching swapped-QK register P);
//   chunks XOR'd by (d>>1)&3 for bank spread.  grid (N/64, 2) x 256 thr.
// ---------------------------------------------------------------------------
__global__ void prep_kernel(const float* __restrict__ q,
                            const float* __restrict__ k,
                            const float* __restrict__ v,
                            bf16_t* __restrict__ qb,
                            bf16_t* __restrict__ kswz,
                            bf16_t* __restrict__ vtswz) {
  __shared__ bf16_t tile[64][72];
  const int bk = blockIdx.x;      // 64-key block -> two 32-key v-tiles
  const int bd = blockIdx.y;      // 64-d half, 0..1
  const int t = threadIdx.x;      // 0..255
  const float sc = 0.12751744f;   // log2(e) / sqrt(128)

  const int row_l = t >> 2;             // 0..63
  const int key = bk * 64 + row_l;

#pragma unroll
  for (int u = 0; u < 2; ++u) {
    const int j = bd * 8 + (t & 3) * 2 + u;   // d-chunk 0..15
    const float4* qs = (const float4*)(q + (size_t)key * ATTN_D + j * 8);
    const float4* ks = (const float4*)(k + (size_t)key * ATTN_D + j * 8);
    float4 a0 = qs[0], a1 = qs[1];
    float4 b0 = ks[0], b1 = ks[1];
    bf16x8 qo, ko;
    qo[0] = (bf16_t)(a0.x * sc); qo[1] = (bf16_t)(a0.y * sc);
    qo[2] = (bf16_t)(a0.z * sc); qo[3] = (bf16_t)(a0.w * sc);
    qo[4] = (bf16_t)(a1.x * sc); qo[5] = (bf16_t)(a1.y * sc);
    qo[6] = (bf16_t)(a1.z * sc); qo[7] = (bf16_t)(a1.w * sc);
    ko[0] = (bf16_t)b0.x; ko[1] = (bf16_t)b0.y;
    ko[2] = (bf16_t)b0.z; ko[3] = (bf16_t)b0.w;
    ko[4] = (bf16_t)b1.x; ko[5] = (bf16_t)b1.y;
    ko[6] = (bf16_t)b1.z; ko[7] = (bf16_t)b1.w;
    *(bf16x8*)(qb + (size_t)key * ATTN_D + j * 8) = qo;
    *(bf16x8*)(kswz + (size_t)key * ATTN_D + ((j ^ (key & 15)) * 8)) = ko;
  }

  {
    const float* src = v + (size_t)key * ATTN_D + bd * 64 + (t & 3) * 16;
#pragma unroll
    for (int u = 0; u < 4; ++u) {
      float4 a = ((const float4*)src)[u];
      tile[row_l][(t & 3) * 16 + u * 4 + 0] = (bf16_t)a.x;
      tile[row_l][(t & 3) * 16 + u * 4 + 1] = (bf16_t)a.y;
      tile[row_l][(t & 3) * 16 + u * 4 + 2] = (bf16_t)a.z;
      tile[row_l][(t & 3) * 16 + u * 4 + 3] = (bf16_t)a.w;
    }
  }
  __syncthreads();
  {
    const int d_l = t >> 2;            // 0..63
    const int d = bd * 64 + d_l;
    const int cq = t & 3;              // chunk 0..3 (key-slots 8cq..8cq+7)
#pragma unroll
    for (int h = 0; h < 2; ++h) {      // two 32-key v-tiles in this block
      bf16x8 o;
#pragma unroll
      for (int j = 0; j < 8; ++j) {
        // slot 8cq+j -> phys key: quad-block interleave for swapped-QK P.
        const int kl_ = h * 32 + ((j & 4) << 2) + 4 * cq + (j & 3);
        o[j] = tile[kl_][d_l];
      }
      *(bf16x8*)(vtswz + (size_t)(2 * bk + h) * TILE_ELEMS + d * TKEYS +
                 ((cq ^ ((d >> 1) & 3)) * 8)) = o;
    }
  }
}

// ---------------------------------------------------------------------------
// Flash attention, 256 queries/block x 8-way split-K, swapped-QK register
// softmax, SUPER-PERIOD barriers (sync once per 4 tiles, 8-deep ring).
//   R12 post-mortem: every config R4-R12 phase-locked all waves with a
//   sync every tile -> all waves hit the LDS port together, then the MFMA
//   pipe together: pipe times ADD. m114: only waves at DIFFERENT phases
//   overlap. Fix without losing tile sharing (1-wave blocks would 8x the
//   L2 traffic, ~30us floor): lengthen the sync period. NBUF=8 x 16 KB
//   (same 128 KB), barrier once per PERIOD=4 tiles:
//     period p: [issue DMA slices for tiles p+4..p+7] ->
//               [compute tiles p..p+3 with ZERO intra-period waits] ->
//               [vmcnt(0) (free: DMAs had ~4 iters to land) ; s_barrier]
//   Residency invariant: tiles p..p+3 were issued at start of period p-1
//   and drained before the barrier that opened period p. Buffer reuse:
//   tiles p+4..p+7 overwrite bufs of tiles p-4..p-1, read-complete before
//   the previous barrier. Waves drift freely across 4 tiles -> one wave's
//   LDS phase overlaps another's MFMA phase.
//   1 block/CU (grid 256), 8 waves x 32 rows, 2 waves/SIMD, ~120 VGPR.
//   Per wave-tile: 16 QK-MFMA + 8 V-preload reads + 16 exp2x2 + 16 PV-MFMA.
//   XCD: blk&7 = key eighth -> each XCD L2 holds 512 KB.
// MFMA layouts (mfma_f32_16x16x32_bf16, verified gfx950):
//   A: m = lane&15, k = (lane>>4)*8 + j
//   B: n = lane&15, k = (lane>>4)*8 + j
//   C/D: n = lane&15 (col), m = (lane>>4)*4 + reg
// ---------------------------------------------------------------------------
__global__ __launch_bounds__(512, 2) void flash_attn_kernel(
    const bf16_t* __restrict__ qb, const bf16_t* __restrict__ kswz,
    const bf16_t* __restrict__ vtswz, float* __restrict__ partO,
    float* __restrict__ partL) {
  __shared__ __align__(16) bf16_t KV[NBUF][2][TILE_ELEMS];  // 128 KB ring

  const int t = threadIdx.x;     // 0..511
  const int w = t >> 6;          // 0..7 = 32-row q subtile
  const int lane = t & 63;
  const int quad = lane >> 4;
  const int col = lane & 15;
  const int blk = blockIdx.x;
  const int qg = blk >> 3;       // 0..31
  const int kh = blk & 7;        // key eighth == XCD
  const int q0 = qg * QROWS;
  const int ktbase = kh * KTPB;
  const int stg = (qg & 3) * 8;  // stagger: decorrelate first-pass L3 streams

#define ISSUE_TILE(itx)                                                       \
  {                                                                           \
    const int nt_ = ktbase + ((stg + (itx)) & (KTPB - 1));                    \
    const int nb_ = (itx) & (NBUF - 1);                                       \
    dma16(kswz + (size_t)nt_ * TILE_ELEMS + t * 8, &KV[nb_][0][t * 8]);       \
    dma16(vtswz + (size_t)nt_ * TILE_ELEMS + t * 8, &KV[nb_][1][t * 8]);      \
  }

  // Swizzled LDS offsets (row*stride + (chunk^swz)*8).
  int offK[4][2], offV[8];
#pragma unroll
  for (int c = 0; c < 4; ++c)
#pragma unroll
    for (int ks = 0; ks < 2; ++ks)
      offK[c][ks] = (ks * 16 + col) * ATTN_D + (((c * 4 + quad) ^ col) * 8);
#pragma unroll
  for (int ds = 0; ds < 8; ++ds)
    offV[ds] = (ds * 16 + col) * TKEYS + ((quad ^ ((col >> 1) & 3)) * 8);

  // Q fragments (B operand): 2 q-subtiles x 4 k-chunks, in regs all kernel.
  bf16x8 aq[2][4];
#pragma unroll
  for (int qs = 0; qs < 2; ++qs) {
    const int row = q0 + w * 32 + qs * 16 + col;
#pragma unroll
    for (int c = 0; c < 4; ++c)
      aq[qs][c] = *(const bf16x8*)(qb + (size_t)row * ATTN_D + c * 32 + quad * 8);
  }

  f32x4 oacc[2][8];
#pragma unroll
  for (int qs = 0; qs < 2; ++qs)
#pragma unroll
    for (int i = 0; i < 8; ++i) oacc[qs][i] = (f32x4){0.f, 0.f, 0.f, 0.f};
  float l_part[2] = {0.f, 0.f};

  // Prologue: tiles 0..3 into bufs 0..3; drain; barrier.
#pragma unroll
  for (int pt = 0; pt < PERIOD; ++pt) ISSUE_TILE(pt);
  asm volatile("s_waitcnt vmcnt(0)" ::: "memory");
  __builtin_amdgcn_s_barrier();

  for (int p = 0; p < KTPB; p += PERIOD) {
    // Issue next period's 4 tiles (bufs of tiles p-4..p-1, read-complete).
    if (p + PERIOD < KTPB) {
#pragma unroll
      for (int j = 0; j < PERIOD; ++j) ISSUE_TILE(p + PERIOD + j);
    }

    // Compute tiles p..p+3 -- no cross-wave sync inside the period.
#pragma unroll
    for (int j = 0; j < PERIOD; ++j) {
      const int it = p + j;
      const bf16_t* Kb = KV[it & (NBUF - 1)][0];
      const bf16_t* Vb = KV[it & (NBUF - 1)][1];

      // --- S = K Q^T (swapped): s[ksub][qs]; lane: q=col, key=quad*4+r.
      f32x4 s[2][2];
#pragma unroll
      for (int ks = 0; ks < 2; ++ks)
#pragma unroll
        for (int qs = 0; qs < 2; ++qs) s[ks][qs] = (f32x4){0.f, 0.f, 0.f, 0.f};
      __builtin_amdgcn_s_setprio(1);
#pragma unroll
      for (int c = 0; c < 4; ++c) {
        bf16x8 k0 = *(const bf16x8*)(Kb + offK[c][0]);
        bf16x8 k1 = *(const bf16x8*)(Kb + offK[c][1]);
        s[0][0] = __builtin_amdgcn_mfma_f32_16x16x32_bf16(k0, aq[0][c], s[0][0], 0, 0, 0);
        s[0][1] = __builtin_amdgcn_mfma_f32_16x16x32_bf16(k0, aq[1][c], s[0][1], 0, 0, 0);
        s[1][0] = __builtin_amdgcn_mfma_f32_16x16x32_bf16(k1, aq[0][c], s[1][0], 0, 0, 0);
        s[1][1] = __builtin_amdgcn_mfma_f32_16x16x32_bf16(k1, aq[1][c], s[1][1], 0, 0, 0);
      }
      __builtin_amdgcn_s_setprio(0);

      // --- V preload (independent of S): drains under the softmax VALU.
      bf16x8 bv[8];
#pragma unroll
      for (int ds = 0; ds < 8; ++ds)
        bv[ds] = *(const bf16x8*)(Vb + offV[ds]);

      // --- p = 2^s, packed to PV A-frag IN REGISTERS (j<4 -> ksub0 key
      //     4*quad+j; j>=4 -> ksub1 key 16+4*quad+j-4; V image matches).
      bf16x8 ap[2];
#pragma unroll
      for (int qs = 0; qs < 2; ++qs) {
        float pa0 = EXP2(s[0][qs][0]), pa1 = EXP2(s[0][qs][1]);
        float pa2 = EXP2(s[0][qs][2]), pa3 = EXP2(s[0][qs][3]);
        float pb0 = EXP2(s[1][qs][0]), pb1 = EXP2(s[1][qs][1]);
        float pb2 = EXP2(s[1][qs][2]), pb3 = EXP2(s[1][qs][3]);
        l_part[qs] += (pa0 + pa1 + pa2 + pa3) + (pb0 + pb1 + pb2 + pb3);
        ap[qs][0] = (bf16_t)pa0; ap[qs][1] = (bf16_t)pa1;
        ap[qs][2] = (bf16_t)pa2; ap[qs][3] = (bf16_t)pa3;
        ap[qs][4] = (bf16_t)pb0; ap[qs][5] = (bf16_t)pb1;
        ap[qs][6] = (bf16_t)pb2; ap[qs][7] = (bf16_t)pb3;
      }

      // --- O += P V: pure-register MFMA.
      __builtin_amdgcn_s_setprio(1);
#pragma unroll
      for (int ds = 0; ds < 8; ++ds) {
        oacc[0][ds] = __builtin_amdgcn_mfma_f32_16x16x32_bf16(ap[0], bv[ds], oacc[0][ds], 0, 0, 0);
        oacc[1][ds] = __builtin_amdgcn_mfma_f32_16x16x32_bf16(ap[1], bv[ds], oacc[1][ds], 0, 0, 0);
      }
      __builtin_amdgcn_s_setprio(0);
    }

    // Period boundary: own DMAs (issued at period start) drained -> after
    // the barrier every wave may assume tiles p+4..p+7 resident.
    asm volatile("s_waitcnt vmcnt(0)" ::: "memory");
    __builtin_amdgcn_s_barrier();
  }

  // --- epilogue: partial L. Lane holds the sum over its 8 keys for q=col;
  //     total over the 32-key tiles = reduce across the 4 quads.
#pragma unroll
  for (int qs = 0; qs < 2; ++qs) {
    float v = l_part[qs];
    v += __shfl_xor(v, 16, 64);
    v += __shfl_xor(v, 32, 64);
    if (quad == 0)
      partL[(size_t)blk * QROWS + w * 32 + qs * 16 + col] = v;
  }

  // --- direct store of this wave's 32 unnormalized O rows.
  {
    float* dst = partO + ((size_t)blk * QROWS + w * 32) * ATTN_D;
#pragma unroll
    for (int qs = 0; qs < 2; ++qs)
#pragma unroll
      for (int ds = 0; ds < 8; ++ds)
#pragma unroll
        for (int r = 0; r < 4; ++r)
          dst[(qs * 16 + quad * 4 + r) * ATTN_D + ds * 16 + col] = oacc[qs][ds][r];
  }
#undef ISSUE_TILE
}

// ---------------------------------------------------------------------------
// Merge: out[row] = (sum of 8 split-K partial O) / (sum of 8 partial L).
//   1024 blocks x 256 threads, one float4 per thread.
// ---------------------------------------------------------------------------
__global__ void merge_kernel(const float* __restrict__ partO,
                             const float* __restrict__ partL,
                             float* __restrict__ out) {
  const int idx = blockIdx.x * blockDim.x + threadIdx.x;  // float4 index
  const int row = idx >> 5;          // 32 float4 per 128-elem row
  const int gi = row >> 8;           // query group 0..31
  const int rl = row & 255;
  const int li = rl * 32 + (idx & 31);
  float L = 0.f;
  float4 acc = {0.f, 0.f, 0.f, 0.f};
#pragma unroll
  for (int i = 0; i < 8; ++i) {
    const size_t b = (size_t)(8 * gi + i);
    L += partL[b * QROWS + rl];
    float4 a = ((const float4*)(partO + b * (QROWS * ATTN_D)))[li];
    acc.x += a.x; acc.y += a.y; acc.z += a.z; acc.w += a.w;
  }
  const float invL = 1.0f / L;
  float4 o;
  o.x = acc.x * invL; o.y = acc.y * invL;
  o.z = acc.z * invL; o.w = acc.w * invL;
  ((float4*)out)[idx] = o;
}

// ---------------------------------------------------------------------------
extern "C" void kernel_launch(void* const* d_in, const int* in_sizes, int n_in,
                              void* d_out, int out_size, void* d_ws, size_t ws_size,
                              hipStream_t stream) {
  const float* q = (const float*)d_in[0];
  const float* k = (const float*)d_in[1];
  const float* v = (const float*)d_in[2];
  float* out = (float*)d_out;

  // Workspace: qb | kswz | vtswz (bf16, 2 MB each) | partO 33.6 MB | partL 256 KB.
  bf16_t* qb = (bf16_t*)d_ws;
  bf16_t* kswz = qb + (size_t)ATTN_N * ATTN_D;
  bf16_t* vtswz = kswz + (size_t)ATTN_N * ATTN_D;
  float* partO = (float*)(vtswz + (size_t)ATTN_N * ATTN_D);
  float* partL = partO + (size_t)256 * QROWS * ATTN_D;

  prep_kernel<<<dim3(ATTN_N / 64, 2), 256, 0, stream>>>(q, k, v, qb, kswz, vtswz);
  flash_attn_kernel<<<256, 512, 0, stream>>>(qb, kswz, vtswz, partO, partL);
  merge_kernel<<<(ATTN_N * ATTN_D / 4) / 256, 256, 0, stream>>>(partO, partL, out);
}

// Round 14
// 103.177 us; speedup vs baseline: 1.0485x; 1.0485x over previous
//
#include <hip/hip_runtime.h>
#include <hip/hip_bf16.h>

#define ATTN_N 8192
#define ATTN_D 128
#define TKEYS 64                      // keys per LDS tile
#define NTILES (ATTN_N / TKEYS)       // 128
#define TILE_ELEMS (TKEYS * ATTN_D)   // 8192 bf16 = 16 KB
#define QROWS 256                     // queries per block (8 waves x 32 rows)
#define SPLITK 8                      // 8-way split-K -> 256 blocks = 1/CU
#define KTPB (NTILES / SPLITK)        // 16 key tiles per block
#define NBUF 4                        // 4-deep LDS ring (128 KB)

typedef __bf16 bf16_t;
typedef _Float16 f16_t;
typedef bf16_t bf16x8 __attribute__((ext_vector_type(8)));
typedef f16_t f16x8 __attribute__((ext_vector_type(8)));
typedef float f32x4 __attribute__((ext_vector_type(4)));

#if __has_builtin(__builtin_amdgcn_exp2f)
#define EXP2(x) __builtin_amdgcn_exp2f(x)
#else
#define EXP2(x) __expf((x) * 0.6931471805599453f)
#endif

// Async global->LDS DMA, 16 B per lane; lane-linear on both sides (m104).
__device__ __forceinline__ void dma16(const bf16_t* g, bf16_t* l) {
  __builtin_amdgcn_global_load_lds(
      (const __attribute__((address_space(1))) void*)g,
      (__attribute__((address_space(3))) void*)l, 16, 0, 0);
}

// ---------------------------------------------------------------------------
// Prep (unchanged, verified): Q -> bf16 linear (scaled by log2(e)/sqrt(128));
//   K -> key-linear swizzled image (chunk j at j ^ (key&15));
//   V -> transposed 64-key tile image, per-32-key-half quad-block interleave
//   matching swapped-QK register P, chunk XOR d&7.  grid (N/64,2) x 256 thr.
// ---------------------------------------------------------------------------
__global__ void prep_kernel(const float* __restrict__ q,
                            const float* __restrict__ k,
                            const float* __restrict__ v,
                            bf16_t* __restrict__ qb,
                            bf16_t* __restrict__ kswz,
                            bf16_t* __restrict__ vtswz) {
  __shared__ bf16_t tile[64][72];
  const int bk = blockIdx.x;      // 64-key block == V tile index, 0..127
  const int bd = blockIdx.y;      // 64-d half, 0..1
  const int t = threadIdx.x;      // 0..255
  const float sc = 0.12751744f;   // log2(e) / sqrt(128)

  const int row_l = t >> 2;             // 0..63
  const int key = bk * 64 + row_l;

#pragma unroll
  for (int u = 0; u < 2; ++u) {
    const int j = bd * 8 + (t & 3) * 2 + u;   // d-chunk 0..15
    const float4* qs = (const float4*)(q + (size_t)key * ATTN_D + j * 8);
    const float4* ks = (const float4*)(k + (size_t)key * ATTN_D + j * 8);
    float4 a0 = qs[0], a1 = qs[1];
    float4 b0 = ks[0], b1 = ks[1];
    bf16x8 qo, ko;
    qo[0] = (bf16_t)(a0.x * sc); qo[1] = (bf16_t)(a0.y * sc);
    qo[2] = (bf16_t)(a0.z * sc); qo[3] = (bf16_t)(a0.w * sc);
    qo[4] = (bf16_t)(a1.x * sc); qo[5] = (bf16_t)(a1.y * sc);
    qo[6] = (bf16_t)(a1.z * sc); qo[7] = (bf16_t)(a1.w * sc);
    ko[0] = (bf16_t)b0.x; ko[1] = (bf16_t)b0.y;
    ko[2] = (bf16_t)b0.z; ko[3] = (bf16_t)b0.w;
    ko[4] = (bf16_t)b1.x; ko[5] = (bf16_t)b1.y;
    ko[6] = (bf16_t)b1.z; ko[7] = (bf16_t)b1.w;
    *(bf16x8*)(qb + (size_t)key * ATTN_D + j * 8) = qo;
    *(bf16x8*)(kswz + (size_t)key * ATTN_D + ((j ^ (key & 15)) * 8)) = ko;
  }

  {
    const float* src = v + (size_t)key * ATTN_D + bd * 64 + (t & 3) * 16;
#pragma unroll
    for (int u = 0; u < 4; ++u) {
      float4 a = ((const float4*)src)[u];
      tile[row_l][(t & 3) * 16 + u * 4 + 0] = (bf16_t)a.x;
      tile[row_l][(t & 3) * 16 + u * 4 + 1] = (bf16_t)a.y;
      tile[row_l][(t & 3) * 16 + u * 4 + 2] = (bf16_t)a.z;
      tile[row_l][(t & 3) * 16 + u * 4 + 3] = (bf16_t)a.w;
    }
  }
  __syncthreads();
  {
    const int d_l = t >> 2;            // 0..63
    const int d = bd * 64 + d_l;
#pragma unroll
    for (int u = 0; u < 2; ++u) {
      const int cc = (t & 3) * 2 + u;  // chunk 0..7 (key-slots 8cc..8cc+7)
      const int h = cc >> 2;           // 32-key half
      const int qd = cc & 3;           // quad
      bf16x8 o;
#pragma unroll
      for (int j = 0; j < 8; ++j) {
        // slot -> phys key: half*32 + quad-block interleave (swapped-QK P).
        const int kl_ = h * 32 + ((j & 4) << 2) + 4 * qd + (j & 3);
        o[j] = tile[kl_][d_l];
      }
      *(bf16x8*)(vtswz + (size_t)bk * TILE_ELEMS + d * TKEYS +
                 ((cc ^ (d & 7)) * 8)) = o;
    }
  }
}

// ---------------------------------------------------------------------------
// Flash attention (R12 core, best measured: 41.3 us): 256 q/block x 8-way
// split-K, swapped-QK register softmax, counted-vmcnt 4-deep ring, 1
// block/CU, V-preload. ONLY change this round: partial O stored as f16
// (f32 accumulate, convert on final store) -- halves partO traffic.
//   Design-space sweep R4-R13 (occupancy, rows/wave, tile size, P in
//   LDS vs regs, sync period, period-2 ILP) all land 41-45 us ~= the
//   documented plain-HIP attn plateau; R12 is the optimum found.
// MFMA layouts (mfma_f32_16x16x32_bf16, verified gfx950):
//   A: m = lane&15, k = (lane>>4)*8 + j
//   B: n = lane&15, k = (lane>>4)*8 + j
//   C/D: n = lane&15 (col), m = (lane>>4)*4 + reg
// ---------------------------------------------------------------------------
__global__ __launch_bounds__(512, 2) void flash_attn_kernel(
    const bf16_t* __restrict__ qb, const bf16_t* __restrict__ kswz,
    const bf16_t* __restrict__ vtswz, f16_t* __restrict__ partO,
    float* __restrict__ partL) {
  __shared__ __align__(16) bf16_t KV[NBUF][2][TILE_ELEMS];  // 128 KB ring

  const int t = threadIdx.x;     // 0..511
  const int w = t >> 6;          // 0..7 = 32-row q subtile
  const int lane = t & 63;
  const int quad = lane >> 4;
  const int col = lane & 15;
  const int blk = blockIdx.x;
  const int qg = blk >> 3;       // 0..31
  const int kh = blk & 7;        // key eighth == XCD
  const int q0 = qg * QROWS;
  const int ktbase = kh * KTPB;
  const int stg = (qg & 3) * 4;  // stagger: decorrelate first-pass L3 streams

#define ISSUE_TILE(itx)                                                       \
  {                                                                           \
    const int nt_ = ktbase + ((stg + (itx)) & (KTPB - 1));                    \
    const int nb_ = (itx) & (NBUF - 1);                                       \
    _Pragma("unroll")                                                         \
    for (int u = 0; u < 2; ++u) {                                             \
      dma16(kswz + (size_t)nt_ * TILE_ELEMS + t * 8 + u * 4096,               \
            &KV[nb_][0][t * 8 + u * 4096]);                                   \
      dma16(vtswz + (size_t)nt_ * TILE_ELEMS + t * 8 + u * 4096,              \
            &KV[nb_][1][t * 8 + u * 4096]);                                   \
    }                                                                         \
  }

  // Swizzled LDS offsets (row*stride + (chunk^swz)*8).
  int offK[4][4], offV[8][2];
#pragma unroll
  for (int c = 0; c < 4; ++c)
#pragma unroll
    for (int ks = 0; ks < 4; ++ks)
      offK[c][ks] = (ks * 16 + col) * ATTN_D + (((c * 4 + quad) ^ col) * 8);
#pragma unroll
  for (int ds = 0; ds < 8; ++ds)
#pragma unroll
    for (int h = 0; h < 2; ++h)
      offV[ds][h] = (ds * 16 + col) * TKEYS + (((h * 4 + quad) ^ (col & 7)) * 8);

  // Q fragments (B operand): 2 q-subtiles x 4 k-chunks, in regs all kernel.
  bf16x8 aq[2][4];
#pragma unroll
  for (int qs = 0; qs < 2; ++qs) {
    const int row = q0 + w * 32 + qs * 16 + col;
#pragma unroll
    for (int c = 0; c < 4; ++c)
      aq[qs][c] = *(const bf16x8*)(qb + (size_t)row * ATTN_D + c * 32 + quad * 8);
  }

  f32x4 oacc[2][8];
#pragma unroll
  for (int qs = 0; qs < 2; ++qs)
#pragma unroll
    for (int i = 0; i < 8; ++i) oacc[qs][i] = (f32x4){0.f, 0.f, 0.f, 0.f};
  float l_part[2] = {0.f, 0.f};

  // Prologue: tiles 0..2 into bufs 0..2 (12 dma16/thread outstanding).
#pragma unroll
  for (int pt = 0; pt < 3; ++pt) ISSUE_TILE(pt);
  asm volatile("s_waitcnt vmcnt(8)" ::: "memory");  // tile 0 landed; 1,2 fly
  __builtin_amdgcn_s_barrier();

  for (int it = 0; it < KTPB; ++it) {
    const int buf = it & (NBUF - 1);
    if (it + 3 < KTPB) ISSUE_TILE(it + 3);
    const bf16_t* Kb = KV[buf][0];
    const bf16_t* Vb = KV[buf][1];

    // --- S = K Q^T (swapped): s[ksub][qs]; lane: q=col, key=ksub*16+quad*4+r.
    f32x4 s[4][2];
#pragma unroll
    for (int ks = 0; ks < 4; ++ks)
#pragma unroll
      for (int qs = 0; qs < 2; ++qs) s[ks][qs] = (f32x4){0.f, 0.f, 0.f, 0.f};
    __builtin_amdgcn_s_setprio(1);
#pragma unroll
    for (int c = 0; c < 4; ++c) {
#pragma unroll
      for (int ks = 0; ks < 4; ++ks) {
        bf16x8 kf = *(const bf16x8*)(Kb + offK[c][ks]);
        s[ks][0] = __builtin_amdgcn_mfma_f32_16x16x32_bf16(kf, aq[0][c], s[ks][0], 0, 0, 0);
        s[ks][1] = __builtin_amdgcn_mfma_f32_16x16x32_bf16(kf, aq[1][c], s[ks][1], 0, 0, 0);
      }
    }
    __builtin_amdgcn_s_setprio(0);

    // --- V PRELOAD (independent of S): drains under the softmax VALU.
    bf16x8 bv[8][2];
#pragma unroll
    for (int ds = 0; ds < 8; ++ds)
#pragma unroll
      for (int h = 0; h < 2; ++h)
        bv[ds][h] = *(const bf16x8*)(Vb + offV[ds][h]);

    // --- p = 2^s, packed to PV A-frags IN REGISTERS. Per 32-key half h:
    //     ap[qs][h][j]: j<4 -> ksub 2h key 4*quad+j; j>=4 -> ksub 2h+1 key
    //     16+4*quad+(j-4). V image uses the same quad-block key order.
    bf16x8 ap[2][2];
#pragma unroll
    for (int qs = 0; qs < 2; ++qs) {
#pragma unroll
      for (int h = 0; h < 2; ++h) {
        float pa0 = EXP2(s[2 * h][qs][0]), pa1 = EXP2(s[2 * h][qs][1]);
        float pa2 = EXP2(s[2 * h][qs][2]), pa3 = EXP2(s[2 * h][qs][3]);
        float pb0 = EXP2(s[2 * h + 1][qs][0]), pb1 = EXP2(s[2 * h + 1][qs][1]);
        float pb2 = EXP2(s[2 * h + 1][qs][2]), pb3 = EXP2(s[2 * h + 1][qs][3]);
        l_part[qs] += (pa0 + pa1 + pa2 + pa3) + (pb0 + pb1 + pb2 + pb3);
        ap[qs][h][0] = (bf16_t)pa0; ap[qs][h][1] = (bf16_t)pa1;
        ap[qs][h][2] = (bf16_t)pa2; ap[qs][h][3] = (bf16_t)pa3;
        ap[qs][h][4] = (bf16_t)pb0; ap[qs][h][5] = (bf16_t)pb1;
        ap[qs][h][6] = (bf16_t)pb2; ap[qs][h][7] = (bf16_t)pb3;
      }
    }

    // --- O += P V over 64 keys (2 halves); all operands in registers.
    __builtin_amdgcn_s_setprio(1);
#pragma unroll
    for (int ds = 0; ds < 8; ++ds) {
#pragma unroll
      for (int h = 0; h < 2; ++h) {
        oacc[0][ds] = __builtin_amdgcn_mfma_f32_16x16x32_bf16(ap[0][h], bv[ds][h], oacc[0][ds], 0, 0, 0);
        oacc[1][ds] = __builtin_amdgcn_mfma_f32_16x16x32_bf16(ap[1][h], bv[ds][h], oacc[1][ds], 0, 0, 0);
      }
    }
    __builtin_amdgcn_s_setprio(0);

    // --- counted wait: tile it+1 landed; tiles it+2/it+3 (8 dma ops) stay
    //     in flight across the barrier (T4). Tail iters drain what's left.
    if (it + 3 < KTPB) {
      asm volatile("s_waitcnt vmcnt(8)" ::: "memory");
      __builtin_amdgcn_s_barrier();
    } else if (it + 2 < KTPB) {
      asm volatile("s_waitcnt vmcnt(4)" ::: "memory");
      __builtin_amdgcn_s_barrier();
    } else if (it + 1 < KTPB) {
      asm volatile("s_waitcnt vmcnt(0)" ::: "memory");
      __builtin_amdgcn_s_barrier();
    }
  }

  // --- epilogue: partial L (f32). Lane holds the sum over its 16 keys for
  //     q=col; total over the 64-key tiles = reduce across the 4 quads.
#pragma unroll
  for (int qs = 0; qs < 2; ++qs) {
    float v = l_part[qs];
    v += __shfl_xor(v, 16, 64);
    v += __shfl_xor(v, 32, 64);
    if (quad == 0)
      partL[(size_t)blk * QROWS + w * 32 + qs * 16 + col] = v;
  }

  // --- direct store of this wave's 32 unnormalized O rows as f16
  //     (f32 accumulate, convert on store only; range <= ~1e3 << 65504).
  {
    f16_t* dst = partO + ((size_t)blk * QROWS + w * 32) * ATTN_D;
#pragma unroll
    for (int qs = 0; qs < 2; ++qs)
#pragma unroll
      for (int ds = 0; ds < 8; ++ds)
#pragma unroll
        for (int r = 0; r < 4; ++r)
          dst[(qs * 16 + quad * 4 + r) * ATTN_D + ds * 16 + col] =
              (f16_t)oacc[qs][ds][r];
  }
#undef ISSUE_TILE
}

// ---------------------------------------------------------------------------
// Merge: out[row] = (sum of 8 split-K f16 partial O) / (sum of 8 f32 L).
//   512 blocks x 256 threads, one f16x8 (16 B) per partial per thread.
// ---------------------------------------------------------------------------
__global__ void merge_kernel(const f16_t* __restrict__ partO,
                             const float* __restrict__ partL,
                             float* __restrict__ out) {
  const int idx = blockIdx.x * blockDim.x + threadIdx.x;  // 8-elem chunk id
  const int row = idx >> 4;          // 16 chunks per 128-elem row
  const int gi = row >> 8;           // query group 0..31
  const int rl = row & 255;
  const int ci = (idx & 15) * 8;     // column offset
  float L = 0.f;
  float acc[8] = {0.f, 0.f, 0.f, 0.f, 0.f, 0.f, 0.f, 0.f};
#pragma unroll
  for (int i = 0; i < 8; ++i) {
    const size_t b = (size_t)(8 * gi + i);
    L += partL[b * QROWS + rl];
    f16x8 a = *(const f16x8*)(partO + b * ((size_t)QROWS * ATTN_D) +
                              (size_t)rl * ATTN_D + ci);
#pragma unroll
    for (int j = 0; j < 8; ++j) acc[j] += (float)a[j];
  }
  const float invL = 1.0f / L;
  float4 o0, o1;
  o0.x = acc[0] * invL; o0.y = acc[1] * invL;
  o0.z = acc[2] * invL; o0.w = acc[3] * invL;
  o1.x = acc[4] * invL; o1.y = acc[5] * invL;
  o1.z = acc[6] * invL; o1.w = acc[7] * invL;
  float* dst = out + (size_t)row * ATTN_D + ci;
  *(float4*)dst = o0;
  *(float4*)(dst + 4) = o1;
}

// ---------------------------------------------------------------------------
extern "C" void kernel_launch(void* const* d_in, const int* in_sizes, int n_in,
                              void* d_out, int out_size, void* d_ws, size_t ws_size,
                              hipStream_t stream) {
  const float* q = (const float*)d_in[0];
  const float* k = (const float*)d_in[1];
  const float* v = (const float*)d_in[2];
  float* out = (float*)d_out;

  // Workspace: qb | kswz | vtswz (bf16, 2 MB each) | partO f16 16.8 MB |
  //            partL f32 256 KB.
  bf16_t* qb = (bf16_t*)d_ws;
  bf16_t* kswz = qb + (size_t)ATTN_N * ATTN_D;
  bf16_t* vtswz = kswz + (size_t)ATTN_N * ATTN_D;
  f16_t* partO = (f16_t*)(vtswz + (size_t)ATTN_N * ATTN_D);
  float* partL = (float*)(partO + (size_t)256 * QROWS * ATTN_D);

  prep_kernel<<<dim3(ATTN_N / 64, 2), 256, 0, stream>>>(q, k, v, qb, kswz, vtswz);
  flash_attn_kernel<<<256, 512, 0, stream>>>(qb, kswz, vtswz, partO, partL);
  merge_kernel<<<(ATTN_N * ATTN_D / 8) / 256, 256, 0, stream>>>(partO, partL, out);
}